// Round 3
// baseline (115.288 us; speedup 1.0000x reference)
//
#include <hip/hip_runtime.h>
#include <hip/hip_cooperative_groups.h>
#include <cmath>

namespace cg = cooperative_groups;

// Problem constants (from reference)
#define B_ROWS    32768
#define IN_DIM    64
#define NUM_BINS  10
#define EMBED_DIM 64
#define NBLK      256   // cooperative grid: 1 block per CU

// ---- monotone float <-> uint key mapping (no NaNs in inputs) ----
__device__ __forceinline__ unsigned f2key(float f) {
    unsigned u = __float_as_uint(f);
    return (u & 0x80000000u) ? ~u : (u | 0x80000000u);
}
__device__ __forceinline__ float key2f(unsigned k) {
    unsigned u = (k & 0x80000000u) ? (k ^ 0x80000000u) : ~k;
    return __uint_as_float(u);
}

// Single fused cooperative kernel. grid=256 x 1024 (1 block/CU, co-resident).
// Phase 1: per-column min/max partials -> ws, grid.sync().
// Phase 2: reduce partials, build bins + M = embed @ W^T, then bucketize +
// wave-ballot histogram + 10-FMA output. Phase-2 rows match phase-1 fetches
// so the x re-read hits this block's own XCD L2.
__global__ __launch_bounds__(1024) void fused_kernel(
    const float* __restrict__ x, const float* __restrict__ logits,
    const float* __restrict__ embed, const float* __restrict__ W,
    const float* __restrict__ bias, unsigned* __restrict__ ws,
    float* __restrict__ out)
{
    __shared__ unsigned smin[IN_DIM], smax[IN_DIM];
    __shared__ float sden[IN_DIM], smn[IN_DIM], sbias[EMBED_DIM];
    __shared__ float sbins[NUM_BINS];
    __shared__ float sM[NUM_BINS * EMBED_DIM];
    __shared__ unsigned pmin[16][IN_DIM], pmax[16][IN_DIM];

    int t = threadIdx.x;
    int b = blockIdx.x;

    // ---------- phase 1: per-column min/max partials ----------
    if (t < IN_DIM) { smin[t] = 0xFFFFFFFFu; smax[t] = 0u; }
    __syncthreads();

    const float4* x4 = (const float4*)x;
    int g = b * 1024 + t;                 // 0..262143; covers x4[g] and x4[g+262144]
    float4 v0 = x4[g];
    float4 v1 = x4[g + 262144];
    int cg4 = (g & 15) * 4;               // fixed 4-column group (262144 % 16 == 0)

    atomicMin(&smin[cg4 + 0], f2key(fminf(v0.x, v1.x)));
    atomicMax(&smax[cg4 + 0], f2key(fmaxf(v0.x, v1.x)));
    atomicMin(&smin[cg4 + 1], f2key(fminf(v0.y, v1.y)));
    atomicMax(&smax[cg4 + 1], f2key(fmaxf(v0.y, v1.y)));
    atomicMin(&smin[cg4 + 2], f2key(fminf(v0.z, v1.z)));
    atomicMax(&smax[cg4 + 2], f2key(fmaxf(v0.z, v1.z)));
    atomicMin(&smin[cg4 + 3], f2key(fminf(v0.w, v1.w)));
    atomicMax(&smax[cg4 + 3], f2key(fmaxf(v0.w, v1.w)));
    __syncthreads();
    if (t < 2 * IN_DIM) {
        unsigned v = (t < IN_DIM) ? smin[t] : smax[t - IN_DIM];
        ws[b * 128 + t] = v;
    }

    cg::this_grid().sync();

    // ---------- phase 2 setup: reduce partials + bins + M ----------
    {
        int col = t & 63, chunk = t >> 6;     // chunk 0..15
        unsigned kmin = 0xFFFFFFFFu, kmax = 0u;
        #pragma unroll
        for (int blk = chunk; blk < NBLK; blk += 16) {
            kmin = min(kmin, ws[blk * 128 + col]);
            kmax = max(kmax, ws[blk * 128 + 64 + col]);
        }
        pmin[chunk][col] = kmin;
        pmax[chunk][col] = kmax;
    }
    __syncthreads();
    if (t < IN_DIM) {
        unsigned kmin = 0xFFFFFFFFu, kmax = 0u;
        #pragma unroll
        for (int c = 0; c < 16; c++) {
            kmin = min(kmin, pmin[c][t]);
            kmax = max(kmax, pmax[c][t]);
        }
        float mn = key2f(kmin);
        float mx = key2f(kmax);
        smn[t]  = mn;
        sden[t] = mx - mn + 1e-6f;            // matches ref: (max - min + EPS)
        sbias[t] = 64.0f * bias[t];           // IN_DIM * b
    }
    if (t == 0) {
        // softmax (max-subtracted, sequential) then cumsum — same op order as ref
        float l[NUM_BINS], e[NUM_BINS];
        float m = -INFINITY;
        #pragma unroll
        for (int i = 0; i < NUM_BINS; i++) { l[i] = logits[i]; m = fmaxf(m, l[i]); }
        float s = 0.0f;
        #pragma unroll
        for (int i = 0; i < NUM_BINS; i++) { e[i] = expf(l[i] - m); s += e[i]; }
        float c = 0.0f;
        #pragma unroll
        for (int i = 0; i < NUM_BINS; i++) { c += e[i] / s; sbins[i] = c; }
    }
    // M[k][f] = sum_e embed[k,e] * W[f,e]   (640 entries; embed/W tiny, cache-hot)
    for (int id = t; id < NUM_BINS * EMBED_DIM; id += 1024) {
        int k = id >> 6, f = id & 63;
        const float* er = embed + k * EMBED_DIM;
        const float* wr = W + f * EMBED_DIM;
        float acc = 0.0f;
        #pragma unroll 8
        for (int e = 0; e < EMBED_DIM; e++) acc += er[e] * wr[e];
        sM[id] = acc;
    }
    __syncthreads();

    // ---------- phase 2 main: one wave per row ----------
    int w = t >> 6;        // wave id 0..15
    int lane = t & 63;     // column
    float cmn = smn[lane], cden = sden[lane], cbias = sbias[lane];

    // rows this block fetched in phase 1: [b*64, b*64+64) and +16384 — L2-hot
    int base = b * 64 + w * 4;
    #pragma unroll
    for (int half = 0; half < 2; half++) {
        int r0 = base + half * 16384;
        #pragma unroll
        for (int q = 0; q < 4; q++) {
            int r = r0 + q;
            float xv = x[r * IN_DIM + lane];
            float xn = (xv - cmn) / cden;             // IEEE div, matches ref bitwise
            int idx = 0;
            #pragma unroll
            for (int k = 0; k < NUM_BINS; k++) idx += (sbins[k] < xn) ? 1 : 0;  // searchsorted left
            if (idx > NUM_BINS - 1) idx = NUM_BINS - 1;   // clip

            float acc = cbias;
            #pragma unroll
            for (int k = 0; k < NUM_BINS; k++) {
                unsigned long long msk = __ballot(idx == k);   // 64-bit wave ballot
                acc = fmaf((float)__popcll(msk), sM[k * EMBED_DIM + lane], acc);
            }
            out[r * EMBED_DIM + lane] = acc;
        }
    }
}

extern "C" void kernel_launch(void* const* d_in, const int* in_sizes, int n_in,
                              void* d_out, int out_size, void* d_ws, size_t ws_size,
                              hipStream_t stream) {
    const float* x      = (const float*)d_in[0];
    const float* logits = (const float*)d_in[1];
    const float* embed  = (const float*)d_in[2];
    const float* W      = (const float*)d_in[3];
    const float* bias   = (const float*)d_in[4];
    float* out = (float*)d_out;
    unsigned* ws = (unsigned*)d_ws;   // 256 blocks x 128 uints of min/max partials

    void* args[] = {(void*)&x, (void*)&logits, (void*)&embed, (void*)&W,
                    (void*)&bias, (void*)&ws, (void*)&out};
    hipLaunchCooperativeKernel((void*)fused_kernel, dim3(NBLK), dim3(1024),
                               args, 0, stream);
}

// Round 4
// 83.385 us; speedup vs baseline: 1.3826x; 1.3826x over previous
//
#include <hip/hip_runtime.h>
#include <cmath>

// Problem constants (from reference)
#define B_ROWS    32768
#define IN_DIM    64
#define NUM_BINS  10
#define EMBED_DIM 64
#define NBLK1     256   // blocks in minmax kernel (partials count)

// ---- monotone float <-> uint key mapping (no NaNs in inputs) ----
__device__ __forceinline__ unsigned f2key(float f) {
    unsigned u = __float_as_uint(f);
    return (u & 0x80000000u) ? ~u : (u | 0x80000000u);
}
__device__ __forceinline__ float key2f(unsigned k) {
    unsigned u = (k & 0x80000000u) ? (k ^ 0x80000000u) : ~k;
    return __uint_as_float(u);
}

// Kernel 1: per-column min/max partials. Block b writes its 64 min keys to
// ws[b*128 .. +63] and 64 max keys to ws[b*128+64 .. +127]. No global
// atomics, no init required (every slot is written unconditionally).
__global__ __launch_bounds__(256) void minmax_kernel(const float* __restrict__ x,
                                                     unsigned* __restrict__ ws) {
    __shared__ unsigned smin[IN_DIM], smax[IN_DIM];
    int t = threadIdx.x;
    if (t < IN_DIM) { smin[t] = 0xFFFFFFFFu; smax[t] = 0u; }
    __syncthreads();

    const float4* x4 = (const float4*)x;
    const int total = B_ROWS * IN_DIM / 4;   // 524288
    const int stride = NBLK1 * 256;          // 65536
    int g = blockIdx.x * 256 + t;
    int cg = (g & 15) * 4;                   // this thread's fixed 4-column group

    float mn0 =  INFINITY, mn1 =  INFINITY, mn2 =  INFINITY, mn3 =  INFINITY;
    float mx0 = -INFINITY, mx1 = -INFINITY, mx2 = -INFINITY, mx3 = -INFINITY;
    #pragma unroll
    for (int i = g; i < total; i += stride) {
        float4 v = x4[i];
        mn0 = fminf(mn0, v.x); mx0 = fmaxf(mx0, v.x);
        mn1 = fminf(mn1, v.y); mx1 = fmaxf(mx1, v.y);
        mn2 = fminf(mn2, v.z); mx2 = fmaxf(mx2, v.z);
        mn3 = fminf(mn3, v.w); mx3 = fmaxf(mx3, v.w);
    }
    atomicMin(&smin[cg + 0], f2key(mn0)); atomicMax(&smax[cg + 0], f2key(mx0));
    atomicMin(&smin[cg + 1], f2key(mn1)); atomicMax(&smax[cg + 1], f2key(mx1));
    atomicMin(&smin[cg + 2], f2key(mn2)); atomicMax(&smax[cg + 2], f2key(mx2));
    atomicMin(&smin[cg + 3], f2key(mn3)); atomicMax(&smax[cg + 3], f2key(mx3));
    __syncthreads();
    if (t < 2 * IN_DIM) {
        unsigned v = (t < IN_DIM) ? smin[t] : smax[t - IN_DIM];
        ws[blockIdx.x * 128 + t] = v;
    }
}

// Kernel 2: reduce partials + bucketize + histogram + tiny matmul.
// grid=256, block=1024 (16 waves). One wave per row; lane = column.
__global__ __launch_bounds__(1024) void main_kernel(
    const float* __restrict__ x, const float* __restrict__ logits,
    const float* __restrict__ embed, const float* __restrict__ W,
    const float* __restrict__ bias, const unsigned* __restrict__ ws,
    float* __restrict__ out)
{
    __shared__ float smn[IN_DIM], sden[IN_DIM], sbias[EMBED_DIM];
    __shared__ float sbins[NUM_BINS];
    __shared__ float sM[NUM_BINS * EMBED_DIM];
    __shared__ unsigned pmin[16][IN_DIM], pmax[16][IN_DIM];

    int t = threadIdx.x;

    // --- stage 1: parallel reduce the 256 per-block partials ---
    {
        int col = t & 63, chunk = t >> 6;    // chunk 0..15
        unsigned kmin = 0xFFFFFFFFu, kmax = 0u;
        #pragma unroll
        for (int b = chunk; b < NBLK1; b += 16) {
            unsigned lo = ws[b * 128 + col];
            unsigned hi = ws[b * 128 + 64 + col];
            kmin = min(kmin, lo);
            kmax = max(kmax, hi);
        }
        pmin[chunk][col] = kmin;
        pmax[chunk][col] = kmax;
    }
    __syncthreads();
    if (t < IN_DIM) {
        unsigned kmin = 0xFFFFFFFFu, kmax = 0u;
        #pragma unroll
        for (int c = 0; c < 16; c++) {
            kmin = min(kmin, pmin[c][t]);
            kmax = max(kmax, pmax[c][t]);
        }
        float mn = key2f(kmin);
        float mx = key2f(kmax);
        smn[t]  = mn;
        sden[t] = mx - mn + 1e-6f;           // matches ref: (max - min + EPS)
        sbias[t] = 64.0f * bias[t];          // IN_DIM * b
    }
    if (t == 0) {
        // softmax (max-subtracted, sequential) then cumsum — same op order as ref
        float l[NUM_BINS], e[NUM_BINS];
        float m = -INFINITY;
        #pragma unroll
        for (int i = 0; i < NUM_BINS; i++) { l[i] = logits[i]; m = fmaxf(m, l[i]); }
        float s = 0.0f;
        #pragma unroll
        for (int i = 0; i < NUM_BINS; i++) { e[i] = expf(l[i] - m); s += e[i]; }
        float c = 0.0f;
        #pragma unroll
        for (int i = 0; i < NUM_BINS; i++) { c += e[i] / s; sbins[i] = c; }
    }
    // M[k][f] = sum_e embed[k,e] * W[f,e]   (640 entries; embed/W are L2-hot)
    for (int id = t; id < NUM_BINS * EMBED_DIM; id += 1024) {
        int k = id >> 6, f = id & 63;
        const float* er = embed + k * EMBED_DIM;
        const float* wr = W + f * EMBED_DIM;
        float acc = 0.0f;
        #pragma unroll 8
        for (int e = 0; e < EMBED_DIM; e++) acc += er[e] * wr[e];
        sM[id] = acc;
    }
    __syncthreads();

    int w = t >> 6;        // wave id 0..15
    int lane = t & 63;     // column
    float cmn = smn[lane], cden = sden[lane], cbias = sbias[lane];

    #pragma unroll
    for (int r = blockIdx.x * 16 + w; r < B_ROWS; r += 256 * 16) {
        float xv = x[r * IN_DIM + lane];
        float xn = (xv - cmn) / cden;                 // IEEE div, matches ref bitwise
        int idx = 0;
        #pragma unroll
        for (int k = 0; k < NUM_BINS; k++) idx += (sbins[k] < xn) ? 1 : 0;  // searchsorted left
        if (idx > NUM_BINS - 1) idx = NUM_BINS - 1;   // clip

        float acc = cbias;
        #pragma unroll
        for (int k = 0; k < NUM_BINS; k++) {
            unsigned long long msk = __ballot(idx == k);   // 64-bit wave ballot
            acc = fmaf((float)__popcll(msk), sM[k * EMBED_DIM + lane], acc);
        }
        out[r * EMBED_DIM + lane] = acc;
    }
}

extern "C" void kernel_launch(void* const* d_in, const int* in_sizes, int n_in,
                              void* d_out, int out_size, void* d_ws, size_t ws_size,
                              hipStream_t stream) {
    const float* x      = (const float*)d_in[0];
    const float* logits = (const float*)d_in[1];
    const float* embed  = (const float*)d_in[2];
    const float* W      = (const float*)d_in[3];
    const float* bias   = (const float*)d_in[4];
    float* out = (float*)d_out;

    unsigned* ws = (unsigned*)d_ws;   // 256 blocks x 128 uints of min/max partials

    minmax_kernel<<<NBLK1, 256, 0, stream>>>(x, ws);
    main_kernel<<<256, 1024, 0, stream>>>(x, logits, embed, W, bias, ws, out);
}